// Round 12
// baseline (546.637 us; speedup 1.0000x reference)
//
#include <hip/hip_runtime.h>
#include <stdint.h>

#define N_NODES 20000
#define N_EDGES 320000

typedef __attribute__((ext_vector_type(8)))  __bf16        bf16x8;
typedef __attribute__((ext_vector_type(16))) float         f32x16;
typedef __attribute__((ext_vector_type(4)))  float         f32x4v;
typedef __attribute__((ext_vector_type(4)))  uint32_t      u32x4;
typedef __attribute__((ext_vector_type(8)))  unsigned short us8;
typedef __attribute__((ext_vector_type(2)))  unsigned short us2;

static __device__ __forceinline__ unsigned short cvt_bf16(float f) {
  uint32_t u = __builtin_bit_cast(uint32_t, f);
  u = (u + 0x7fffu + ((u >> 16) & 1u)) >> 16;
  return (unsigned short)u;
}
static __device__ __forceinline__ float cvt_f32(unsigned short h) {
  uint32_t u = ((uint32_t)h) << 16;
  return __builtin_bit_cast(float, u);
}

// async global->LDS, 16B per lane; LDS dest = wave-uniform base (HW adds lane*16)
static __device__ __forceinline__ void gll16(const void* g, void* l) {
  __builtin_amdgcn_global_load_lds(
      (const __attribute__((address_space(1))) unsigned int*)g,
      (__attribute__((address_space(3))) unsigned int*)l, 16, 0, 0);
}

// literal-folded counted vmcnt wait
#define WAITV(n) do { \
  if ((n) == 0)      asm volatile("s_waitcnt vmcnt(0)" ::: "memory"); \
  else if ((n) == 4) asm volatile("s_waitcnt vmcnt(4)" ::: "memory"); \
  else if ((n) == 8) asm volatile("s_waitcnt vmcnt(8)" ::: "memory"); \
  else               asm volatile("s_waitcnt vmcnt(12)" ::: "memory"); \
} while (0)

// counted LDS wait + scheduling fence (rule #18: stop MFMA hoisting past it)
#define WAITL8 do { asm volatile("s_waitcnt lgkmcnt(8)" ::: "memory"); \
                    __builtin_amdgcn_sched_barrier(0); } while (0)
#define WAITL0 do { asm volatile("s_waitcnt lgkmcnt(0)" ::: "memory"); \
                    __builtin_amdgcn_sched_barrier(0); } while (0)

// ---------------------------------------------------------------------------
// pack_w: natural k-order fragments (verified R1-R11).
// out[((ks*(N/32)+nt)*64+ln)*8+e] = W[ks*16+(ln>>5)*8+e][nt*32+(ln&31)]
// ---------------------------------------------------------------------------
__global__ void pack_w(const float* __restrict__ W, unsigned short* __restrict__ out,
                       int K, int Ncols) {
  int idx = blockIdx.x * 256 + threadIdx.x;
  int total = K * Ncols;
  if (idx >= total) return;
  int e    = idx & 7;
  int lane = (idx >> 3) & 63;
  int t    = idx >> 9;
  int ntiles = Ncols >> 5;
  int nt = t % ntiles;
  int ks = t / ntiles;
  int k = ks * 16 + (lane >> 5) * 8 + e;
  int c = nt * 32 + (lane & 31);
  out[idx] = cvt_bf16(W[(size_t)k * Ncols + c]);
}

// ---------------------------------------------------------------------------
// pack_w2: sigma k-order for the register-resident H handoff (verified R6-R11).
// sigma(ks,g,e) = ks*16 + g*4 + (e&3) + 8*(e>>2)
// ---------------------------------------------------------------------------
__global__ void pack_w2(const float* __restrict__ W, unsigned short* __restrict__ out) {
  int idx = blockIdx.x * 256 + threadIdx.x;     // 32768 total
  if (idx >= 32768) return;
  int e    = idx & 7;
  int lane = (idx >> 3) & 63;
  int t    = idx >> 9;          // frag = ks*4 + nt
  int nt = t & 3, ks = t >> 2;
  int k = ks * 16 + ((lane >> 5) << 2) + (e & 3) + ((e >> 2) << 3);
  int c = nt * 32 + (lane & 31);
  out[idx] = cvt_bf16(W[(size_t)k * 128 + c]);
}

// ---------------------------------------------------------------------------
// CSR build for segment_sum (receivers constant across iterations)
// ---------------------------------------------------------------------------
__global__ void hist_k(const int* __restrict__ recv, int* __restrict__ cnt, int n) {
  int i = blockIdx.x * 256 + threadIdx.x;
  if (i < n) atomicAdd(&cnt[recv[i]], 1);
}

__global__ void scan_k(const int* __restrict__ cnt, int* __restrict__ off,
                       int* __restrict__ cursor, int n) {
  __shared__ int part[1024];
  int t = threadIdx.x;
  int chunk = (n + 1023) / 1024;
  int base = t * chunk;
  int s = 0;
  for (int i = 0; i < chunk; ++i) { int idx = base + i; if (idx < n) s += cnt[idx]; }
  part[t] = s;
  __syncthreads();
  for (int d = 1; d < 1024; d <<= 1) {
    int v = (t >= d) ? part[t - d] : 0;
    __syncthreads();
    part[t] += v;
    __syncthreads();
  }
  int prefix = (t > 0) ? part[t - 1] : 0;
  for (int i = 0; i < chunk; ++i) {
    int idx = base + i;
    if (idx < n) { off[idx] = prefix; cursor[idx] = prefix; prefix += cnt[idx]; }
  }
  if (t == 1023) off[n] = part[1023];
}

__global__ void fill_k(const int* __restrict__ recv, int* __restrict__ cursor,
                       int* __restrict__ eid, int n) {
  int i = blockIdx.x * 256 + threadIdx.x;
  if (i < n) {
    int p = atomicAdd(&cursor[recv[i]], 1);
    eid[p] = i;
  }
}

// agg[n][:] = sum_{edges -> n} e[edge][:], f32 accumulate, bf16 out
__global__ void agg_k(const unsigned short* __restrict__ eb, const int* __restrict__ off,
                      const int* __restrict__ eid, unsigned short* __restrict__ aggb, int n) {
  int node = blockIdx.x * 4 + (threadIdx.x >> 6);
  if (node >= n) return;
  int lane = threadIdx.x & 63;
  float a0 = 0.f, a1 = 0.f;
  int s = off[node], t = off[node + 1];
  for (int q = s; q < t; ++q) {
    int ei = eid[q];
    us2 v = *(const us2*)(eb + (size_t)ei * 128 + lane * 2);
    a0 += cvt_f32(v[0]);
    a1 += cvt_f32(v[1]);
  }
  us2 r; r[0] = cvt_bf16(a0); r[1] = cvt_bf16(a1);
  *(us2*)(aggb + (size_t)node * 128 + lane * 2) = r;
}

// ---------------------------------------------------------------------------
// Fused 2-layer MLP: out = relu(relu(A@W1+b1)@W2+b2), hidden 256, out 128.
// 128 rows/block, 4 waves; wave-tile = FULL 256 hidden x 32 rows.
// L1 flipped; H handoff IN REGISTERS (sigma order, verified R6-R11).
// R12: m201-style BATCHED LDS reads. The R6-R11 COMPUTE let the compiler
// interleave dependent {ds_read av -> mfma} chains, exposing LDS latency on
// every MFMA (measured: 7.5k cyc/phase vs 2k pure-MFMA, no pipe saturated).
// Now each phase: issue 2x8 ds_reads -> fill latency with row-consume +
// prefetch issue -> {lgkmcnt(8) + sched_barrier; 8 pure-reg MFMAs; issue
// next 8 ds_reads} ... -> lgkmcnt(0) tail. Same for the L2 chunk phases.
// Buffer rotation / barriers / vmcnt bookkeeping unchanged from R11.
// ---------------------------------------------------------------------------
template <int KIN, int MODE, int POOL>
__global__ __launch_bounds__(256, 2)
void mlp_kernel(const float* __restrict__ srcf,
                const unsigned short* __restrict__ xb,
                const unsigned short* __restrict__ ebuf,
                const unsigned short* __restrict__ aggb,
                const int* __restrict__ senders,
                const int* __restrict__ receivers,
                const unsigned short* __restrict__ P1,
                const float* __restrict__ b1,
                const unsigned short* __restrict__ P2,
                const float* __restrict__ b2,
                unsigned short* __restrict__ dst,
                float* __restrict__ pool_out,
                int nrows) {
  constexpr int NS1 = KIN / 32;                 // 4 / 12 / 8 (even)
  constexpr int NP  = NS1 / 2;                  // phases
  __shared__ __align__(16) unsigned char lds[65536];   // 4 x 16KB rotation

  const int tid  = threadIdx.x;
  const int lane = tid & 63;
  const int wid  = tid >> 6;     // 0..3
  const int g    = lane >> 5;
  const int l31  = lane & 31;
  const int rowBlock = blockIdx.x << 7;

  const unsigned char* P1b = (const unsigned char*)P1;
  const unsigned char* P2b = (const unsigned char*)P2;

  int grow = rowBlock + wid * 32 + l31;
  if (grow >= nrows) grow = nrows - 1;

  const unsigned short *pS = nullptr, *pR = nullptr, *pE = nullptr;
  const unsigned short *pX = nullptr, *pAg = nullptr;
  const float* fb = nullptr;
  if constexpr (MODE == 0) {
    fb = srcf + (size_t)grow * KIN;
  } else if constexpr (MODE == 1) {
    pS = xb + (size_t)senders[grow] * 128;
    pR = xb + (size_t)receivers[grow] * 128;
    pE = ebuf + (size_t)grow * 128;
  } else {
    pX  = xb + (size_t)grow * 128;
    pAg = aggb + (size_t)grow * 128;
  }

  auto STG1 = [&](int s) {
    unsigned char* bW = lds + (s & 3) * 16384;
#pragma unroll
    for (int c = 0; c < 4; ++c)
      gll16(P1b + (size_t)s * 16384 + c * 4096 + tid * 16,
            bW + c * 4096 + wid * 1024);
  };
  auto STG2 = [&](int c) {
    unsigned char* bW = lds + ((c + NS1) & 3) * 16384;
#pragma unroll
    for (int q = 0; q < 4; ++q)
      gll16(P2b + (size_t)c * 16384 + q * 4096 + tid * 16,
            bW + q * 4096 + wid * 1024);
  };

  auto LROW = [&](int s, us8* o) {
    const int k0s = s * 32;
    const unsigned short* p;
    if constexpr (MODE == 1) {
      const int seg = k0s >> 7;
      p = (seg == 0) ? pS : (seg == 1) ? pR : pE;
    } else {
      p = (k0s >> 7) ? pAg : pX;
    }
    const int ko = k0s & 127;
    o[0] = *(const us8*)(p + ko + g * 8);
    o[1] = *(const us8*)(p + ko + 16 + g * 8);
  };
  auto LROWF = [&](int s, f32x4v* rf) {
    const float* p = fb + s * 32 + g * 8;
    rf[0] = *(const f32x4v*)(p);
    rf[1] = *(const f32x4v*)(p + 4);
    rf[2] = *(const f32x4v*)(p + 16);
    rf[3] = *(const f32x4v*)(p + 20);
  };
  auto MKBR = [&](const f32x4v* rf, bf16x8& b0v, bf16x8& b1v) {
    us8 h0, h1;
#pragma unroll
    for (int e = 0; e < 4; ++e) {
      h0[e] = cvt_bf16(rf[0][e]); h0[4 + e] = cvt_bf16(rf[1][e]);
      h1[e] = cvt_bf16(rf[2][e]); h1[4 + e] = cvt_bf16(rf[3][e]);
    }
    b0v = __builtin_bit_cast(bf16x8, h0);
    b1v = __builtin_bit_cast(bf16x8, h1);
  };

  // ================= layer 1 =================
  f32x16 acc1[8];
#pragma unroll
  for (int t = 0; t < 8; ++t)
#pragma unroll
    for (int k = 0; k < 16; ++k) acc1[t][k] = 0.0f;

  // batched fragment loaders / pure-MFMA bursts
  us8 f0[8], f1[8];
  auto DSB1 = [&](const unsigned char* bW, int kc, us8* f) {
#pragma unroll
    for (int nt = 0; nt < 8; ++nt)
      f[nt] = *(const us8*)(bW + (kc * 8 + nt) * 1024 + lane * 16);
  };
  auto MM8_1 = [&](const us8* f, bf16x8 bv) {
    __builtin_amdgcn_s_setprio(1);
#pragma unroll
    for (int nt = 0; nt < 8; ++nt)
      acc1[nt] = __builtin_amdgcn_mfma_f32_32x32x16_bf16(
          __builtin_bit_cast(bf16x8, f[nt]), bv, acc1[nt], 0, 0, 0);
    __builtin_amdgcn_s_setprio(0);
  };

  us8    rr[4][2];   // MODE 1/2: 4-slot row rotation (compile-time indexed)
  f32x4v rf[4][4];   // MODE 0

  // prologue: W1 steps 0,1 + rows for phases 0,1 (steps 0..3)
  STG1(0); STG1(1);
  if constexpr (MODE == 0) { LROWF(0, rf[0]); LROWF(1, rf[1]); LROWF(2, rf[2]); LROWF(3, rf[3]); }
  else                     { LROW(0, rr[0]);  LROW(1, rr[1]);  LROW(2, rr[2]);  LROW(3, rr[3]); }

#pragma unroll
  for (int p = 0; p < NP; ++p) {
    const int s0 = 2 * p, s1 = 2 * p + 1;
    const unsigned char* B0 = lds + (s0 & 3) * 16384;
    const unsigned char* B1 = lds + (s1 & 3) * 16384;
    // wait leaves only next-phase rows in flight
    const int w = (p + 1 < NP) ? ((MODE == 0) ? 8 : 4) : 0;
    WAITV(w);
    asm volatile("s_waitcnt lgkmcnt(0)" ::: "memory");
    asm volatile("s_barrier" ::: "memory");

    // issue first 16 fragment reads immediately (latency covered below)
    DSB1(B0, 0, f0);
    DSB1(B0, 1, f1);

    // consume rows into locals (R10 WAR fix), then issue next-phase VMEM
    bf16x8 a0v, a1v, c0v, c1v;
    if constexpr (MODE == 0) { MKBR(rf[s0 & 3], a0v, a1v); MKBR(rf[s1 & 3], c0v, c1v); }
    else {
      a0v = __builtin_bit_cast(bf16x8, rr[s0 & 3][0]); a1v = __builtin_bit_cast(bf16x8, rr[s0 & 3][1]);
      c0v = __builtin_bit_cast(bf16x8, rr[s1 & 3][0]); c1v = __builtin_bit_cast(bf16x8, rr[s1 & 3][1]);
    }
    if (p + 1 < NP) {
      STG1(s0 + 2); STG1(s1 + 2);
      if (p + 2 < NP) {
        if constexpr (MODE == 0) { LROWF(s0 + 4, rf[(s0 + 4) & 3]); LROWF(s1 + 4, rf[(s1 + 4) & 3]); }
        else                     { LROW(s0 + 4, rr[(s0 + 4) & 3]);  LROW(s1 + 4, rr[(s1 + 4) & 3]); }
      }
    }

    // pipelined batches: wait(8) -> 8 MFMAs -> issue next 8 reads
    WAITL8;  MM8_1(f0, a0v);  DSB1(B1, 0, f0);
    WAITL8;  MM8_1(f1, a1v);  DSB1(B1, 1, f1);
    WAITL8;  MM8_1(f0, c0v);
    WAITL0;  MM8_1(f1, c1v);
  }

  // W2 chunks 0,1 -> bufs (NS1)&3,(NS1+1)&3: distinct from the two bufs the
  // final L1 phase read -> safe without a barrier.
  STG2(0);
  STG2(1);

  // ===== epilogue 1: bias+relu+cvt -> sigma-order A-frags (registers) =====
  u32x4 pa4[16];
#pragma unroll
  for (int t = 0; t < 8; ++t) {
#pragma unroll
    for (int q4 = 0; q4 < 4; ++q4) {
      const f32x4v bv4 = *(const f32x4v*)(b1 + t * 32 + q4 * 8 + g * 4);
      float v0 = fmaxf(acc1[t][q4 * 4 + 0] + bv4[0], 0.0f);
      float v1 = fmaxf(acc1[t][q4 * 4 + 1] + bv4[1], 0.0f);
      float v2 = fmaxf(acc1[t][q4 * 4 + 2] + bv4[2], 0.0f);
      float v3 = fmaxf(acc1[t][q4 * 4 + 3] + bv4[3], 0.0f);
      uint32_t lo, hi;
      asm("v_cvt_pk_bf16_f32 %0, %1, %2" : "=v"(lo) : "v"(v0), "v"(v1));
      asm("v_cvt_pk_bf16_f32 %0, %1, %2" : "=v"(hi) : "v"(v2), "v"(v3));
      pa4[t * 2 + (q4 >> 1)][(q4 & 1) * 2 + 0] = lo;
      pa4[t * 2 + (q4 >> 1)][(q4 & 1) * 2 + 1] = hi;
    }
  }

  // ================= layer 2: 2 chunk-pair phases, batched reads ===========
  f32x16 acc2[4];
#pragma unroll
  for (int nt = 0; nt < 4; ++nt)
#pragma unroll
    for (int k = 0; k < 16; ++k) acc2[nt][k] = 0.0f;

  auto DSB2 = [&](const unsigned char* bW, int h, us8* f) {
#pragma unroll
    for (int j = 0; j < 8; ++j)
      f[j] = *(const us8*)(bW + ((h * 2 + (j >> 2)) * 4 + (j & 3)) * 1024 + lane * 16);
  };
  auto MM8_2 = [&](const us8* f, int c, int h) {
    __builtin_amdgcn_s_setprio(1);
#pragma unroll
    for (int j = 0; j < 8; ++j) {
      const int kk = h * 2 + (j >> 2);
      acc2[j & 3] = __builtin_amdgcn_mfma_f32_32x32x16_bf16(
          __builtin_bit_cast(bf16x8, pa4[c * 4 + kk]),
          __builtin_bit_cast(bf16x8, f[j]), acc2[j & 3], 0, 0, 0);
    }
    __builtin_amdgcn_s_setprio(0);
  };

#pragma unroll
  for (int q = 0; q < 2; ++q) {
    const int c0 = q * 2, c1 = q * 2 + 1;
    const unsigned char* W0 = lds + ((c0 + NS1) & 3) * 16384;
    const unsigned char* W1c = lds + ((c1 + NS1) & 3) * 16384;
    WAITV(0);
    asm volatile("s_waitcnt lgkmcnt(0)" ::: "memory");
    asm volatile("s_barrier" ::: "memory");
    DSB2(W0, 0, f0);
    DSB2(W0, 1, f1);
    if (q == 0) { STG2(2); STG2(3); }   // bufs freed by the q0 barrier
    WAITL8;  MM8_2(f0, c0, 0);  DSB2(W1c, 0, f0);
    WAITL8;  MM8_2(f1, c0, 1);  DSB2(W1c, 1, f1);
    WAITL8;  MM8_2(f0, c1, 0);
    WAITL0;  MM8_2(f1, c1, 1);
  }

  // ===== epilogue 2: bias+relu, bf16 stores, fused pool =====
  float bias2[4];
#pragma unroll
  for (int nt = 0; nt < 4; ++nt) bias2[nt] = b2[nt * 32 + l31];

#pragma unroll
  for (int reg = 0; reg < 16; ++reg) {
    const int rowpat = (reg & 3) + ((reg >> 2) << 3) + g * 4;
    const int row = rowBlock + wid * 32 + rowpat;
    float vs = 0.0f;
#pragma unroll
    for (int nt = 0; nt < 4; ++nt) {
      float v = fmaxf(acc2[nt][reg] + bias2[nt], 0.0f);
      vs += v;
      if (row < nrows) dst[(size_t)row * 128 + nt * 32 + l31] = cvt_bf16(v);
    }
    if constexpr (POOL) {
#pragma unroll
      for (int m = 1; m <= 16; m <<= 1) vs += __shfl_xor(vs, m, 64);
      if (l31 == 0 && row < nrows) pool_out[row] = vs;
    }
  }
}

// ---------------------------------------------------------------------------
// Workspace layout (bytes)
// ---------------------------------------------------------------------------
static constexpr size_t OFF_X    = 0;                          // N*128*2
static constexpr size_t OFF_E    = 5120000;                    // E*128*2
static constexpr size_t OFF_AGG  = 87040000;                   // N*128*2 (bf16)
static constexpr size_t OFF_PN1  = 92160000;                   // 65536
static constexpr size_t OFF_PN2  = OFF_PN1 + 65536;
static constexpr size_t OFF_PE1  = OFF_PN2 + 65536;
static constexpr size_t OFF_PE2  = OFF_PE1 + 65536;
static constexpr size_t OFF_PD1  = OFF_PE2 + 65536;            // 196608
static constexpr size_t OFF_PD2  = OFF_PD1 + 196608;
static constexpr size_t OFF_PM1  = OFF_PD2 + 65536;            // 131072
static constexpr size_t OFF_PM2  = OFF_PM1 + 131072;
static constexpr size_t OFF_CNT  = OFF_PM2 + 65536;            // N*4
static constexpr size_t OFF_OFFS = OFF_CNT + 80000;            // (N+1)*4
static constexpr size_t OFF_CUR  = OFF_OFFS + 80004;           // N*4
static constexpr size_t OFF_EID  = OFF_CUR + 80000;            // E*4

extern "C" void kernel_launch(void* const* d_in, const int* in_sizes, int n_in,
                              void* d_out, int out_size, void* d_ws, size_t ws_size,
                              hipStream_t stream) {
  const float* nodes = (const float*)d_in[0];
  const float* edges = (const float*)d_in[1];
  const int* senders = (const int*)d_in[2];
  const int* receivers = (const int*)d_in[3];
  const float* Wn1 = (const float*)d_in[4];  const float* bn1 = (const float*)d_in[5];
  const float* Wn2 = (const float*)d_in[6];  const float* bn2 = (const float*)d_in[7];
  const float* We1 = (const float*)d_in[8];  const float* be1 = (const float*)d_in[9];
  const float* We2 = (const float*)d_in[10]; const float* be2 = (const float*)d_in[11];
  const float* Wed1 = (const float*)d_in[12]; const float* bed1 = (const float*)d_in[13];
  const float* Wed2 = (const float*)d_in[14]; const float* bed2 = (const float*)d_in[15];
  const float* Wnd1 = (const float*)d_in[16]; const float* bnd1 = (const float*)d_in[17];
  const float* Wnd2 = (const float*)d_in[18]; const float* bnd2 = (const float*)d_in[19];

  char* ws = (char*)d_ws;
  unsigned short* xb   = (unsigned short*)(ws + OFF_X);
  unsigned short* eb   = (unsigned short*)(ws + OFF_E);
  unsigned short* aggb = (unsigned short*)(ws + OFF_AGG);
  unsigned short* Pn1  = (unsigned short*)(ws + OFF_PN1);
  unsigned short* Pn2  = (unsigned short*)(ws + OFF_PN2);
  unsigned short* Pe1  = (unsigned short*)(ws + OFF_PE1);
  unsigned short* Pe2  = (unsigned short*)(ws + OFF_PE2);
  unsigned short* Pd1  = (unsigned short*)(ws + OFF_PD1);
  unsigned short* Pd2  = (unsigned short*)(ws + OFF_PD2);
  unsigned short* Pm1  = (unsigned short*)(ws + OFF_PM1);
  unsigned short* Pm2  = (unsigned short*)(ws + OFF_PM2);
  int* cnt    = (int*)(ws + OFF_CNT);
  int* offs   = (int*)(ws + OFF_OFFS);
  int* cursor = (int*)(ws + OFF_CUR);
  int* eid    = (int*)(ws + OFF_EID);
  float* outp = (float*)d_out;

  // W1 matrices: natural k-order; W2 matrices: sigma k-order (all 256x128)
  pack_w<<<128, 256, 0, stream>>>(Wn1, Pn1, 128, 256);
  pack_w2<<<128, 256, 0, stream>>>(Wn2, Pn2);
  pack_w<<<128, 256, 0, stream>>>(We1, Pe1, 128, 256);
  pack_w2<<<128, 256, 0, stream>>>(We2, Pe2);
  pack_w<<<384, 256, 0, stream>>>(Wed1, Pd1, 384, 256);
  pack_w2<<<128, 256, 0, stream>>>(Wed2, Pd2);
  pack_w<<<256, 256, 0, stream>>>(Wnd1, Pm1, 256, 256);
  pack_w2<<<128, 256, 0, stream>>>(Wnd2, Pm2);

  // CSR for segment_sum over receivers
  hipMemsetAsync(cnt, 0, (size_t)N_NODES * 4, stream);
  hist_k<<<1250, 256, 0, stream>>>(receivers, cnt, N_EDGES);
  scan_k<<<1, 1024, 0, stream>>>(cnt, offs, cursor, N_NODES);
  fill_k<<<1250, 256, 0, stream>>>(receivers, cursor, eid, N_EDGES);

  const int nodeBlocks = (N_NODES + 127) / 128;  // 157
  const int edgeBlocks = N_EDGES / 128;          // 2500

  // embed stage
  mlp_kernel<128, 0, 0><<<nodeBlocks, 256, 0, stream>>>(
      nodes, nullptr, nullptr, nullptr, nullptr, nullptr,
      Pn1, bn1, Pn2, bn2, xb, nullptr, N_NODES);
  mlp_kernel<128, 0, 0><<<edgeBlocks, 256, 0, stream>>>(
      edges, nullptr, nullptr, nullptr, nullptr, nullptr,
      Pe1, be1, Pe2, be2, eb, nullptr, N_EDGES);

  for (int it = 0; it < 2; ++it) {
    mlp_kernel<384, 1, 0><<<edgeBlocks, 256, 0, stream>>>(
        nullptr, xb, eb, nullptr, senders, receivers,
        Pd1, bed1, Pd2, bed2, eb, nullptr, N_EDGES);
    agg_k<<<(N_NODES + 3) / 4, 256, 0, stream>>>(eb, offs, eid, aggb, N_NODES);
    mlp_kernel<256, 2, 1><<<nodeBlocks, 256, 0, stream>>>(
        nullptr, xb, nullptr, aggb, nullptr, nullptr,
        Pm1, bnd1, Pm2, bnd2, xb, outp + (size_t)it * N_NODES, N_NODES);
  }
}

// Round 13
// 497.673 us; speedup vs baseline: 1.0984x; 1.0984x over previous
//
#include <hip/hip_runtime.h>
#include <stdint.h>

#define N_NODES 20000
#define N_EDGES 320000

typedef __attribute__((ext_vector_type(8)))  __bf16        bf16x8;
typedef __attribute__((ext_vector_type(16))) float         f32x16;
typedef __attribute__((ext_vector_type(4)))  float         f32x4v;
typedef __attribute__((ext_vector_type(4)))  uint32_t      u32x4;
typedef __attribute__((ext_vector_type(8)))  unsigned short us8;
typedef __attribute__((ext_vector_type(2)))  unsigned short us2;

static __device__ __forceinline__ unsigned short cvt_bf16(float f) {
  uint32_t u = __builtin_bit_cast(uint32_t, f);
  u = (u + 0x7fffu + ((u >> 16) & 1u)) >> 16;
  return (unsigned short)u;
}
static __device__ __forceinline__ float cvt_f32(unsigned short h) {
  uint32_t u = ((uint32_t)h) << 16;
  return __builtin_bit_cast(float, u);
}

// async global->LDS, 16B per lane; LDS dest = wave-uniform base (HW adds lane*16)
static __device__ __forceinline__ void gll16(const void* g, void* l) {
  __builtin_amdgcn_global_load_lds(
      (const __attribute__((address_space(1))) unsigned int*)g,
      (__attribute__((address_space(3))) unsigned int*)l, 16, 0, 0);
}

// literal-folded counted vmcnt wait (indices constant after full unroll)
#define WAITV(n) do { \
  if ((n) == 0)      asm volatile("s_waitcnt vmcnt(0)" ::: "memory"); \
  else if ((n) == 4) asm volatile("s_waitcnt vmcnt(4)" ::: "memory"); \
  else if ((n) == 8) asm volatile("s_waitcnt vmcnt(8)" ::: "memory"); \
  else               asm volatile("s_waitcnt vmcnt(12)" ::: "memory"); \
} while (0)

// ---------------------------------------------------------------------------
// pack_w: natural k-order fragments (verified R1-R12).
// out[((ks*(N/32)+nt)*64+ln)*8+e] = W[ks*16+(ln>>5)*8+e][nt*32+(ln&31)]
// ---------------------------------------------------------------------------
__global__ void pack_w(const float* __restrict__ W, unsigned short* __restrict__ out,
                       int K, int Ncols) {
  int idx = blockIdx.x * 256 + threadIdx.x;
  int total = K * Ncols;
  if (idx >= total) return;
  int e    = idx & 7;
  int lane = (idx >> 3) & 63;
  int t    = idx >> 9;
  int ntiles = Ncols >> 5;
  int nt = t % ntiles;
  int ks = t / ntiles;
  int k = ks * 16 + (lane >> 5) * 8 + e;
  int c = nt * 32 + (lane & 31);
  out[idx] = cvt_bf16(W[(size_t)k * Ncols + c]);
}

// ---------------------------------------------------------------------------
// pack_w2: sigma k-order for the register-resident H handoff (verified R6-R12).
// sigma(ks,g,e) = ks*16 + g*4 + (e&3) + 8*(e>>2)
// ---------------------------------------------------------------------------
__global__ void pack_w2(const float* __restrict__ W, unsigned short* __restrict__ out) {
  int idx = blockIdx.x * 256 + threadIdx.x;     // 32768 total
  if (idx >= 32768) return;
  int e    = idx & 7;
  int lane = (idx >> 3) & 63;
  int t    = idx >> 9;          // frag = ks*4 + nt
  int nt = t & 3, ks = t >> 2;
  int k = ks * 16 + ((lane >> 5) << 2) + (e & 3) + ((e >> 2) << 3);
  int c = nt * 32 + (lane & 31);
  out[idx] = cvt_bf16(W[(size_t)k * 128 + c]);
}

// ---------------------------------------------------------------------------
// CSR build for segment_sum (receivers constant across iterations).
// R13: fill_k also emits pos[edge] = sorted position; e is stored PERMANENTLY
// in receiver-sorted order so agg reads contiguous rows.
// ---------------------------------------------------------------------------
__global__ void hist_k(const int* __restrict__ recv, int* __restrict__ cnt, int n) {
  int i = blockIdx.x * 256 + threadIdx.x;
  if (i < n) atomicAdd(&cnt[recv[i]], 1);
}

__global__ void scan_k(const int* __restrict__ cnt, int* __restrict__ off,
                       int* __restrict__ cursor, int n) {
  __shared__ int part[1024];
  int t = threadIdx.x;
  int chunk = (n + 1023) / 1024;
  int base = t * chunk;
  int s = 0;
  for (int i = 0; i < chunk; ++i) { int idx = base + i; if (idx < n) s += cnt[idx]; }
  part[t] = s;
  __syncthreads();
  for (int d = 1; d < 1024; d <<= 1) {
    int v = (t >= d) ? part[t - d] : 0;
    __syncthreads();
    part[t] += v;
    __syncthreads();
  }
  int prefix = (t > 0) ? part[t - 1] : 0;
  for (int i = 0; i < chunk; ++i) {
    int idx = base + i;
    if (idx < n) { off[idx] = prefix; cursor[idx] = prefix; prefix += cnt[idx]; }
  }
  if (t == 1023) off[n] = part[1023];
}

__global__ void fill_k(const int* __restrict__ recv, int* __restrict__ cursor,
                       int* __restrict__ pos, int n) {
  int i = blockIdx.x * 256 + threadIdx.x;
  if (i < n) {
    int p = atomicAdd(&cursor[recv[i]], 1);
    pos[i] = p;
  }
}

// agg[n][:] = sum of CONTIGUOUS sorted e rows [off[n], off[n+1]) — streaming.
__global__ void agg_k(const unsigned short* __restrict__ eb, const int* __restrict__ off,
                      unsigned short* __restrict__ aggb, int n) {
  int node = blockIdx.x * 4 + (threadIdx.x >> 6);
  if (node >= n) return;
  int lane = threadIdx.x & 63;
  float a0 = 0.f, a1 = 0.f;
  int s = off[node], t = off[node + 1];
  for (int q = s; q < t; ++q) {
    us2 v = *(const us2*)(eb + (size_t)q * 128 + lane * 2);
    a0 += cvt_f32(v[0]);
    a1 += cvt_f32(v[1]);
  }
  us2 r; r[0] = cvt_bf16(a0); r[1] = cvt_bf16(a1);
  *(us2*)(aggb + (size_t)node * 128 + lane * 2) = r;
}

// ---------------------------------------------------------------------------
// Fused 2-layer MLP: out = relu(relu(A@W1+b1)@W2+b2), hidden 256, out 128.
// 128 rows/block, 4 waves; wave-tile = FULL 256 hidden x 32 rows.
// L1 flipped; H handoff IN REGISTERS (sigma order, verified R6-R12).
// Pipeline = R11 (two K-steps/phase, 4x16KB rotation, one barrier/phase,
// 2-phase-ahead row prefetch with consume-before-clobber, NS1-shifted W2).
// R13: optional `perm` — MODE 0 writes dst rows at perm[row]; MODE 1 reads
// its e-input at perm[grow] and writes at perm[row] (e lives in
// receiver-sorted order so agg is a contiguous stream).
// ---------------------------------------------------------------------------
template <int KIN, int MODE, int POOL>
__global__ __launch_bounds__(256, 2)
void mlp_kernel(const float* __restrict__ srcf,
                const unsigned short* __restrict__ xb,
                const unsigned short* __restrict__ ebuf,
                const unsigned short* __restrict__ aggb,
                const int* __restrict__ senders,
                const int* __restrict__ receivers,
                const int* __restrict__ perm,
                const unsigned short* __restrict__ P1,
                const float* __restrict__ b1,
                const unsigned short* __restrict__ P2,
                const float* __restrict__ b2,
                unsigned short* __restrict__ dst,
                float* __restrict__ pool_out,
                int nrows) {
  constexpr int NS1 = KIN / 32;                 // 4 / 12 / 8 (even)
  constexpr int NP  = NS1 / 2;                  // phases
  __shared__ __align__(16) unsigned char lds[65536];   // 4 x 16KB rotation

  const int tid  = threadIdx.x;
  const int lane = tid & 63;
  const int wid  = tid >> 6;     // 0..3
  const int g    = lane >> 5;
  const int l31  = lane & 31;
  const int rowBlock = blockIdx.x << 7;

  const unsigned char* P1b = (const unsigned char*)P1;
  const unsigned char* P2b = (const unsigned char*)P2;

  int grow = rowBlock + wid * 32 + l31;
  if (grow >= nrows) grow = nrows - 1;

  const unsigned short *pS = nullptr, *pR = nullptr, *pE = nullptr;
  const unsigned short *pX = nullptr, *pAg = nullptr;
  const float* fb = nullptr;
  if constexpr (MODE == 0) {
    fb = srcf + (size_t)grow * KIN;
  } else if constexpr (MODE == 1) {
    pS = xb + (size_t)senders[grow] * 128;
    pR = xb + (size_t)receivers[grow] * 128;
    pE = ebuf + (size_t)perm[grow] * 128;     // e stored receiver-sorted
  } else {
    pX  = xb + (size_t)grow * 128;
    pAg = aggb + (size_t)grow * 128;
  }

  auto STG1 = [&](int s) {
    unsigned char* bW = lds + (s & 3) * 16384;
#pragma unroll
    for (int c = 0; c < 4; ++c)
      gll16(P1b + (size_t)s * 16384 + c * 4096 + tid * 16,
            bW + c * 4096 + wid * 1024);
  };
  auto STG2 = [&](int c) {
    unsigned char* bW = lds + ((c + NS1) & 3) * 16384;
#pragma unroll
    for (int q = 0; q < 4; ++q)
      gll16(P2b + (size_t)c * 16384 + q * 4096 + tid * 16,
            bW + q * 4096 + wid * 1024);
  };

  auto LROW = [&](int s, us8* o) {
    const int k0s = s * 32;
    const unsigned short* p;
    if constexpr (MODE == 1) {
      const int seg = k0s >> 7;
      p = (seg == 0) ? pS : (seg == 1) ? pR : pE;
    } else {
      p = (k0s >> 7) ? pAg : pX;
    }
    const int ko = k0s & 127;
    o[0] = *(const us8*)(p + ko + g * 8);
    o[1] = *(const us8*)(p + ko + 16 + g * 8);
  };
  auto LROWF = [&](int s, f32x4v* rf) {
    const float* p = fb + s * 32 + g * 8;
    rf[0] = *(const f32x4v*)(p);
    rf[1] = *(const f32x4v*)(p + 4);
    rf[2] = *(const f32x4v*)(p + 16);
    rf[3] = *(const f32x4v*)(p + 20);
  };
  auto MKBR = [&](const f32x4v* rf, bf16x8& b0v, bf16x8& b1v) {
    us8 h0, h1;
#pragma unroll
    for (int e = 0; e < 4; ++e) {
      h0[e] = cvt_bf16(rf[0][e]); h0[4 + e] = cvt_bf16(rf[1][e]);
      h1[e] = cvt_bf16(rf[2][e]); h1[4 + e] = cvt_bf16(rf[3][e]);
    }
    b0v = __builtin_bit_cast(bf16x8, h0);
    b1v = __builtin_bit_cast(bf16x8, h1);
  };

  // ================= layer 1 =================
  f32x16 acc1[8];
#pragma unroll
  for (int t = 0; t < 8; ++t)
#pragma unroll
    for (int k = 0; k < 16; ++k) acc1[t][k] = 0.0f;

  auto COMPUTE = [&](const unsigned char* bW, bf16x8 b0v, bf16x8 b1v) {
#pragma unroll
    for (int kc = 0; kc < 2; ++kc) {
      const bf16x8 bv = kc ? b1v : b0v;
#pragma unroll
      for (int nt = 0; nt < 8; ++nt) {
        bf16x8 av = __builtin_bit_cast(bf16x8,
            *(const us8*)(bW + (kc * 8 + nt) * 1024 + lane * 16));
        acc1[nt] = __builtin_amdgcn_mfma_f32_32x32x16_bf16(av, bv, acc1[nt], 0, 0, 0);
      }
    }
  };

  us8    rr[4][2];   // MODE 1/2: 4-slot row rotation (compile-time indexed)
  f32x4v rf[4][4];   // MODE 0

  // prologue: W1 steps 0,1 + rows for phases 0,1 (steps 0..3)
  STG1(0); STG1(1);
  if constexpr (MODE == 0) { LROWF(0, rf[0]); LROWF(1, rf[1]); LROWF(2, rf[2]); LROWF(3, rf[3]); }
  else                     { LROW(0, rr[0]);  LROW(1, rr[1]);  LROW(2, rr[2]);  LROW(3, rr[3]); }

#pragma unroll
  for (int p = 0; p < NP; ++p) {
    const int s0 = 2 * p, s1 = 2 * p + 1;
    const int w = (p + 1 < NP) ? ((MODE == 0) ? 8 : 4) : 0;
    WAITV(w);
    asm volatile("s_waitcnt lgkmcnt(0)" ::: "memory");
    asm volatile("s_barrier" ::: "memory");

    // consume rows into locals FIRST (WAR fix), then issue next-phase VMEM
    bf16x8 a0v, a1v, c0v, c1v;
    if constexpr (MODE == 0) { MKBR(rf[s0 & 3], a0v, a1v); MKBR(rf[s1 & 3], c0v, c1v); }
    else {
      a0v = __builtin_bit_cast(bf16x8, rr[s0 & 3][0]); a1v = __builtin_bit_cast(bf16x8, rr[s0 & 3][1]);
      c0v = __builtin_bit_cast(bf16x8, rr[s1 & 3][0]); c1v = __builtin_bit_cast(bf16x8, rr[s1 & 3][1]);
    }

    if (p + 1 < NP) {
      STG1(s0 + 2); STG1(s1 + 2);
      if (p + 2 < NP) {
        if constexpr (MODE == 0) { LROWF(s0 + 4, rf[(s0 + 4) & 3]); LROWF(s1 + 4, rf[(s1 + 4) & 3]); }
        else                     { LROW(s0 + 4, rr[(s0 + 4) & 3]);  LROW(s1 + 4, rr[(s1 + 4) & 3]); }
      }
    }

    __builtin_amdgcn_s_setprio(1);
    COMPUTE(lds + (s0 & 3) * 16384, a0v, a1v);
    COMPUTE(lds + (s1 & 3) * 16384, c0v, c1v);
    __builtin_amdgcn_s_setprio(0);
  }

  // W2 chunks 0,1 -> bufs (NS1)&3,(NS1+1)&3: distinct from the two bufs the
  // final L1 phase read -> safe without a barrier.
  STG2(0);
  STG2(1);

  // ===== epilogue 1: bias+relu+cvt -> sigma-order A-frags (registers) =====
  u32x4 pa4[16];
#pragma unroll
  for (int t = 0; t < 8; ++t) {
#pragma unroll
    for (int q4 = 0; q4 < 4; ++q4) {
      const f32x4v bv4 = *(const f32x4v*)(b1 + t * 32 + q4 * 8 + g * 4);
      float v0 = fmaxf(acc1[t][q4 * 4 + 0] + bv4[0], 0.0f);
      float v1 = fmaxf(acc1[t][q4 * 4 + 1] + bv4[1], 0.0f);
      float v2 = fmaxf(acc1[t][q4 * 4 + 2] + bv4[2], 0.0f);
      float v3 = fmaxf(acc1[t][q4 * 4 + 3] + bv4[3], 0.0f);
      uint32_t lo, hi;
      asm("v_cvt_pk_bf16_f32 %0, %1, %2" : "=v"(lo) : "v"(v0), "v"(v1));
      asm("v_cvt_pk_bf16_f32 %0, %1, %2" : "=v"(hi) : "v"(v2), "v"(v3));
      pa4[t * 2 + (q4 >> 1)][(q4 & 1) * 2 + 0] = lo;
      pa4[t * 2 + (q4 >> 1)][(q4 & 1) * 2 + 1] = hi;
    }
  }

  // ================= layer 2: 2 chunk-pair phases =================
  f32x16 acc2[4];
#pragma unroll
  for (int nt = 0; nt < 4; ++nt)
#pragma unroll
    for (int k = 0; k < 16; ++k) acc2[nt][k] = 0.0f;

#pragma unroll
  for (int q = 0; q < 2; ++q) {
    WAITV(0);
    asm volatile("s_waitcnt lgkmcnt(0)" ::: "memory");
    asm volatile("s_barrier" ::: "memory");
    if (q == 0) { STG2(2); STG2(3); }   // bufs freed by the q0 barrier
    __builtin_amdgcn_s_setprio(1);
#pragma unroll
    for (int ci = 0; ci < 2; ++ci) {
      const int c = q * 2 + ci;
      const unsigned char* bW = lds + ((c + NS1) & 3) * 16384;
#pragma unroll
      for (int kk = 0; kk < 4; ++kk) {
        const bf16x8 a2 = __builtin_bit_cast(bf16x8, pa4[c * 4 + kk]);
#pragma unroll
        for (int nt = 0; nt < 4; ++nt) {
          const bf16x8 bw = __builtin_bit_cast(bf16x8,
              *(const us8*)(bW + (kk * 4 + nt) * 1024 + lane * 16));
          acc2[nt] = __builtin_amdgcn_mfma_f32_32x32x16_bf16(a2, bw, acc2[nt], 0, 0, 0);
        }
      }
    }
    __builtin_amdgcn_s_setprio(0);
  }

  // ===== epilogue 2: bias+relu, bf16 stores (optionally perm'd), pool =====
  float bias2[4];
#pragma unroll
  for (int nt = 0; nt < 4; ++nt) bias2[nt] = b2[nt * 32 + l31];

#pragma unroll
  for (int reg = 0; reg < 16; ++reg) {
    const int rowpat = (reg & 3) + ((reg >> 2) << 3) + g * 4;
    const int row = rowBlock + wid * 32 + rowpat;
    const bool ok = (row < nrows);
    size_t drow = 0;
    if (ok) drow = (size_t)((MODE <= 1 && perm) ? perm[row] : row);
    float vs = 0.0f;
#pragma unroll
    for (int nt = 0; nt < 4; ++nt) {
      float v = fmaxf(acc2[nt][reg] + bias2[nt], 0.0f);
      vs += v;
      if (ok) dst[drow * 128 + nt * 32 + l31] = cvt_bf16(v);
    }
    if constexpr (POOL) {
#pragma unroll
      for (int m = 1; m <= 16; m <<= 1) vs += __shfl_xor(vs, m, 64);
      if (l31 == 0 && ok) pool_out[row] = vs;
    }
  }
}

// ---------------------------------------------------------------------------
// Workspace layout (bytes)
// ---------------------------------------------------------------------------
static constexpr size_t OFF_X    = 0;                          // N*128*2
static constexpr size_t OFF_E    = 5120000;                    // E*128*2 (sorted order)
static constexpr size_t OFF_AGG  = 87040000;                   // N*128*2 (bf16)
static constexpr size_t OFF_PN1  = 92160000;                   // 65536
static constexpr size_t OFF_PN2  = OFF_PN1 + 65536;
static constexpr size_t OFF_PE1  = OFF_PN2 + 65536;
static constexpr size_t OFF_PE2  = OFF_PE1 + 65536;
static constexpr size_t OFF_PD1  = OFF_PE2 + 65536;            // 196608
static constexpr size_t OFF_PD2  = OFF_PD1 + 196608;
static constexpr size_t OFF_PM1  = OFF_PD2 + 65536;            // 131072
static constexpr size_t OFF_PM2  = OFF_PM1 + 131072;
static constexpr size_t OFF_CNT  = OFF_PM2 + 65536;            // N*4
static constexpr size_t OFF_OFFS = OFF_CNT + 80000;            // (N+1)*4
static constexpr size_t OFF_CUR  = OFF_OFFS + 80004;           // N*4
static constexpr size_t OFF_POS  = OFF_CUR + 80000;            // E*4

extern "C" void kernel_launch(void* const* d_in, const int* in_sizes, int n_in,
                              void* d_out, int out_size, void* d_ws, size_t ws_size,
                              hipStream_t stream) {
  const float* nodes = (const float*)d_in[0];
  const float* edges = (const float*)d_in[1];
  const int* senders = (const int*)d_in[2];
  const int* receivers = (const int*)d_in[3];
  const float* Wn1 = (const float*)d_in[4];  const float* bn1 = (const float*)d_in[5];
  const float* Wn2 = (const float*)d_in[6];  const float* bn2 = (const float*)d_in[7];
  const float* We1 = (const float*)d_in[8];  const float* be1 = (const float*)d_in[9];
  const float* We2 = (const float*)d_in[10]; const float* be2 = (const float*)d_in[11];
  const float* Wed1 = (const float*)d_in[12]; const float* bed1 = (const float*)d_in[13];
  const float* Wed2 = (const float*)d_in[14]; const float* bed2 = (const float*)d_in[15];
  const float* Wnd1 = (const float*)d_in[16]; const float* bnd1 = (const float*)d_in[17];
  const float* Wnd2 = (const float*)d_in[18]; const float* bnd2 = (const float*)d_in[19];

  char* ws = (char*)d_ws;
  unsigned short* xb   = (unsigned short*)(ws + OFF_X);
  unsigned short* eb   = (unsigned short*)(ws + OFF_E);
  unsigned short* aggb = (unsigned short*)(ws + OFF_AGG);
  unsigned short* Pn1  = (unsigned short*)(ws + OFF_PN1);
  unsigned short* Pn2  = (unsigned short*)(ws + OFF_PN2);
  unsigned short* Pe1  = (unsigned short*)(ws + OFF_PE1);
  unsigned short* Pe2  = (unsigned short*)(ws + OFF_PE2);
  unsigned short* Pd1  = (unsigned short*)(ws + OFF_PD1);
  unsigned short* Pd2  = (unsigned short*)(ws + OFF_PD2);
  unsigned short* Pm1  = (unsigned short*)(ws + OFF_PM1);
  unsigned short* Pm2  = (unsigned short*)(ws + OFF_PM2);
  int* cnt    = (int*)(ws + OFF_CNT);
  int* offs   = (int*)(ws + OFF_OFFS);
  int* cursor = (int*)(ws + OFF_CUR);
  int* pos    = (int*)(ws + OFF_POS);
  float* outp = (float*)d_out;

  // W1 matrices: natural k-order; W2 matrices: sigma k-order (all 256x128)
  pack_w<<<128, 256, 0, stream>>>(Wn1, Pn1, 128, 256);
  pack_w2<<<128, 256, 0, stream>>>(Wn2, Pn2);
  pack_w<<<128, 256, 0, stream>>>(We1, Pe1, 128, 256);
  pack_w2<<<128, 256, 0, stream>>>(We2, Pe2);
  pack_w<<<384, 256, 0, stream>>>(Wed1, Pd1, 384, 256);
  pack_w2<<<128, 256, 0, stream>>>(Wed2, Pd2);
  pack_w<<<256, 256, 0, stream>>>(Wnd1, Pm1, 256, 256);
  pack_w2<<<128, 256, 0, stream>>>(Wnd2, Pm2);

  // CSR for segment_sum over receivers; pos[] = edge -> sorted position
  hipMemsetAsync(cnt, 0, (size_t)N_NODES * 4, stream);
  hist_k<<<1250, 256, 0, stream>>>(receivers, cnt, N_EDGES);
  scan_k<<<1, 1024, 0, stream>>>(cnt, offs, cursor, N_NODES);
  fill_k<<<1250, 256, 0, stream>>>(receivers, cursor, pos, N_EDGES);

  const int nodeBlocks = (N_NODES + 127) / 128;  // 157
  const int edgeBlocks = N_EDGES / 128;          // 2500

  // embed stage (edge embeds written receiver-sorted via pos)
  mlp_kernel<128, 0, 0><<<nodeBlocks, 256, 0, stream>>>(
      nodes, nullptr, nullptr, nullptr, nullptr, nullptr, nullptr,
      Pn1, bn1, Pn2, bn2, xb, nullptr, N_NODES);
  mlp_kernel<128, 0, 0><<<edgeBlocks, 256, 0, stream>>>(
      edges, nullptr, nullptr, nullptr, nullptr, nullptr, pos,
      Pe1, be1, Pe2, be2, eb, nullptr, N_EDGES);

  for (int it = 0; it < 2; ++it) {
    mlp_kernel<384, 1, 0><<<edgeBlocks, 256, 0, stream>>>(
        nullptr, xb, eb, nullptr, senders, receivers, pos,
        Pd1, bed1, Pd2, bed2, eb, nullptr, N_EDGES);
    agg_k<<<(N_NODES + 3) / 4, 256, 0, stream>>>(eb, offs, aggb, N_NODES);
    mlp_kernel<256, 2, 1><<<nodeBlocks, 256, 0, stream>>>(
        nullptr, xb, nullptr, aggb, nullptr, nullptr, nullptr,
        Pm1, bnd1, Pm2, bnd2, xb, outp + (size_t)it * N_NODES, N_NODES);
  }
}